// Round 16
// baseline (3682.388 us; speedup 1.0000x reference)
//
#include <hip/hip_runtime.h>

#define SEQ 2048
#define D 128

typedef float v2f __attribute__((ext_vector_type(2)));
typedef float v4f __attribute__((ext_vector_type(4)));
#define LO2(v) __builtin_shufflevector(v, v, 0, 1)
#define HI2(v) __builtin_shufflevector(v, v, 2, 3)

// ---------------------------------------------------------------------------
// Kernel 1: per-step J-independent quantities (fully parallel), UNNORMALIZED:
//   alpha_i  = k_s . q_i      (i <= s)
//   kqq[s]   = sum alpha_i^2          = l * (k^T Sqq_l k)
//   sl[s]    = sum alpha_i (v_s.v_i)  = l * (k^T Sqv_l v)
//   vv[s]    = v_s . v_s
//   U[s][c]  = sum_i q_i[c] alpha_i   = l * (Sqq_l k)[c]
//   invl[s]  = 1.0 / l   (fp64, for cost rescale)
// Adjacency scalars (for the scan's lagged-matvec corrections):
//   kq_adj[s] = k_{s-1} . q_s ; vv_adj[s] = v_s . v_{s-1} ; kU_adj[s] = k_{s-1} . U_s
// ---------------------------------------------------------------------------
__global__ __launch_bounds__(256) void precompute_kernel(
    const float* __restrict__ q, const float* __restrict__ k, const float* __restrict__ v,
    float* __restrict__ U, float* __restrict__ sl, float* __restrict__ kqq,
    float* __restrict__ vv, float* __restrict__ kq_adj, float* __restrict__ vv_adj,
    float* __restrict__ kU_adj, double* __restrict__ invl)
{
    const int s = blockIdx.x;
    const int tid = threadIdx.x;

    __shared__ float ks[D];
    __shared__ float vs[D];
    __shared__ float alpha[SEQ];
    __shared__ float red[8];
    __shared__ float upart[256];

    if (tid < D) ks[tid] = k[s * D + tid];
    else if (tid < 2 * D) vs[tid - D] = v[s * D + (tid - D)];
    __syncthreads();

    float p_a2 = 0.f, p_ab = 0.f;
    for (int i = tid; i <= s; i += 256) {
        const float4* qr = (const float4*)(q + (size_t)i * D);
        const float4* vr = (const float4*)(v + (size_t)i * D);
        float a = 0.f, b = 0.f;
#pragma unroll
        for (int j = 0; j < D / 4; ++j) {
            float4 q4 = qr[j];
            float4 v4 = vr[j];
            a += q4.x * ks[4 * j + 0] + q4.y * ks[4 * j + 1] + q4.z * ks[4 * j + 2] + q4.w * ks[4 * j + 3];
            b += v4.x * vs[4 * j + 0] + v4.y * vs[4 * j + 1] + v4.z * vs[4 * j + 2] + v4.w * vs[4 * j + 3];
        }
        alpha[i] = a;
        p_a2 += a * a;
        p_ab += a * b;
        if (i == s) vv[s] = b;  // v_s . v_s
    }
#pragma unroll
    for (int off = 1; off < 64; off <<= 1) {
        p_a2 += __shfl_xor(p_a2, off);
        p_ab += __shfl_xor(p_ab, off);
    }
    const int wid = tid >> 6;
    if ((tid & 63) == 0) { red[wid] = p_a2; red[4 + wid] = p_ab; }
    __syncthreads();  // also makes alpha[] visible to everyone
    if (tid == 0) {
        kqq[s] = red[0] + red[1] + red[2] + red[3];
        sl[s]  = red[4] + red[5] + red[6] + red[7];
        invl[s] = 1.0 / (double)(s + 1);
    }

    // ---- adjacency dots: wave 0 -> kq_adj[s+1], wave 1 -> vv_adj[s] ----
    if (tid < 64) {
        if (s + 1 < SEQ) {
            float p2 = ks[tid] * q[(size_t)(s + 1) * D + tid]
                     + ks[tid + 64] * q[(size_t)(s + 1) * D + 64 + tid];
#pragma unroll
            for (int off = 1; off < 64; off <<= 1) p2 += __shfl_xor(p2, off);
            if (tid == 0) kq_adj[s + 1] = p2;
        }
        if (s == 0 && tid == 0) { kq_adj[0] = 0.f; kU_adj[0] = 0.f; vv_adj[0] = 0.f; }
    } else if (tid < 128 && s > 0) {
        const int t2 = tid - 64;
        float p2 = vs[t2] * v[(size_t)(s - 1) * D + t2]
                 + vs[t2 + 64] * v[(size_t)(s - 1) * D + 64 + t2];
#pragma unroll
        for (int off = 1; off < 64; off <<= 1) p2 += __shfl_xor(p2, off);
        if (t2 == 0) vv_adj[s] = p2;
    }

    // pass 2: U[s][c] = sum_i q[i][c] * alpha[i], i parity-split over h,
    // 4 independent accumulators to break the dependent fma chain
    const int c = tid & (D - 1);
    const int h = tid >> 7;  // 0 or 1
    float a0 = 0.f, a1 = 0.f, a2 = 0.f, a3 = 0.f;
    int i = h;
    for (; i + 6 <= s; i += 8) {
        a0 = fmaf(q[(size_t)(i    ) * D + c], alpha[i    ], a0);
        a1 = fmaf(q[(size_t)(i + 2) * D + c], alpha[i + 2], a1);
        a2 = fmaf(q[(size_t)(i + 4) * D + c], alpha[i + 4], a2);
        a3 = fmaf(q[(size_t)(i + 6) * D + c], alpha[i + 6], a3);
    }
    for (; i <= s; i += 2) a0 = fmaf(q[(size_t)i * D + c], alpha[i], a0);
    upart[tid] = (a0 + a1) + (a2 + a3);
    __syncthreads();

    // U store + kU_adj[s] = k_{s-1}.U_s
    float kup = 0.f;
    if (tid < D) {
        const float uv = upart[tid] + upart[tid + D];
        U[(size_t)s * D + tid] = uv;
        if (s > 0) kup = uv * k[(size_t)(s - 1) * D + tid];
    }
#pragma unroll
    for (int off = 1; off < 64; off <<= 1) kup += __shfl_xor(kup, off);
    if (tid == 0)  red[0] = kup;
    if (tid == 64) red[1] = kup;
    __syncthreads();
    if (s > 0 && tid == 0) kU_adj[s] = red[0] + red[1];
}

// ---------------------------------------------------------------------------
// DPP helpers (R7/R10/R11-verified):
// ---------------------------------------------------------------------------
#define DPP_ADD(x, ctrl) \
    ((x) + __int_as_float(__builtin_amdgcn_update_dpp(0, __float_as_int(x), (ctrl), 0xf, 0xf, true)))
#define COMBINE8(x) do { x = DPP_ADD(x, 0xB1); x = DPP_ADD(x, 0x4E); x = DPP_ADD(x, 0x141); } while (0)
#define TAIL3(x)    do { x = DPP_ADD(x, 0x140); x = DPP_ADD(x, 0x142); x = DPP_ADD(x, 0x143); } while (0)
#define REDUCE16(x) do { x = DPP_ADD(x, 0xB1); x = DPP_ADD(x, 0x4E); x = DPP_ADD(x, 0x141); \
                         x = DPP_ADD(x, 0x140); } while (0)

// packed-fp32 rank-1 update; uses j0..j7, k0_..k7_ (register-resident k_i),
// vcur from enclosing scope
#define UPDATE_J(MODE, WF, WI)                                                \
    if ((MODE) == 2) {                                                        \
        const v2f vc2 = {vcur, vcur};                                         \
        j0 = vc2 * k0_; j1 = vc2 * k1_; j2 = vc2 * k2_; j3 = vc2 * k3_;       \
        j4 = vc2 * k4_; j5 = vc2 * k5_; j6 = vc2 * k6_; j7 = vc2 * k7_;       \
    } else if ((MODE) == 1) {                                                 \
        const v2f wf2 = {(WF), (WF)};                                         \
        const float wvr_ = (WI) * vcur;                                       \
        const v2f wv2 = {wvr_, wvr_};                                         \
        j0 = __builtin_elementwise_fma(j0, wf2, wv2 * k0_);                   \
        j1 = __builtin_elementwise_fma(j1, wf2, wv2 * k1_);                   \
        j2 = __builtin_elementwise_fma(j2, wf2, wv2 * k2_);                   \
        j3 = __builtin_elementwise_fma(j3, wf2, wv2 * k3_);                   \
        j4 = __builtin_elementwise_fma(j4, wf2, wv2 * k4_);                   \
        j5 = __builtin_elementwise_fma(j5, wf2, wv2 * k5_);                   \
        j6 = __builtin_elementwise_fma(j6, wf2, wv2 * k6_);                   \
        j7 = __builtin_elementwise_fma(j7, wf2, wv2 * k7_);                   \
    }

// ---------------------------------------------------------------------------
// Kernel 2: sequential scan, 1024 threads (16 waves, 4/SIMD).
// ROUND-16 = R15 skeleton + k REMOVED from the LDS ring (DS-pipe relief):
//   DS-pipe model: R15 issued 192 ds_read_b128/step on the CU's single LDS
//   pipe (~8-12 cyc each ~= 1550-2300 cyc/step) — the dominant serial
//   resource. k_i is now carried in 8 v2f REGISTERS, refilled by a
//   POST-barrier global prefetch of k_{i+1} each iteration (R13's idea +
//   R14's placement: ~1900 cyc of cover, no barrier-drain exposure, and the
//   J-update no longer waits on any LDS read). DS reads: 192 -> 128/step;
//   stagers shrink to waves 6-9 (q,u only).
// ---------------------------------------------------------------------------
__global__ __launch_bounds__(1024, 4) void scan_kernel(
    const float* __restrict__ q, const float* __restrict__ k, const float* __restrict__ v,
    const float* __restrict__ U, const float* __restrict__ sl_arr,
    const float* __restrict__ kqq_arr, const float* __restrict__ vv_arr,
    const float* __restrict__ kq_adj, const float* __restrict__ vv_adj,
    const float* __restrict__ kU_adj, const double* __restrict__ invl_arr,
    float* __restrict__ out)  // [0,2048) costs | [2048,4096) updated | [4096,...) J
{
    const int tid  = threadIdx.x;
    const int lane = tid & 63;
    const int w    = __builtin_amdgcn_readfirstlane(tid >> 6);  // 0..15
    const int r    = tid >> 3;        // my row 0..127
    const int cg   = tid & 7;
    const int c0s  = cg * 20;         // swizzled LDS chunk offset

    v2f j0 = {0.f, 0.f}, j1 = j0, j2 = j0, j3 = j0, j4 = j0, j5 = j0, j6 = j0, j7 = j0;
    v2f k0_, k1_, k2_, k3_, k4_, k5_, k6_, k7_;   // register-resident k_i

    __shared__ float ring[3][2][160];                 // [phase][q,u][swizzled]
    __shared__ __align__(16) float wred[3][16][4];    // [phase][wave][r1,r2,r3,r4]
    __shared__ __align__(16) float decLDS[3][4];      // [phase][wf,wi,mode,-]

    // stagers: waves 6..9 (tid 384..639) — q,u only; wave0 stays staging-free
    const bool stager = (tid >= 384) && (tid < 640);
    const int  which  = (tid >> 7) - 3;    // 0:q 1:u (when stager)
    const int  sidx   = tid & 127;
    const int  widx   = ((sidx >> 4) * 20) + (sidx & 15);  // swizzled write idx

    // ---- prologue: stage phases 0,1; gstage holds phase-2 data ----
    // invariant: phase j holds q_{j+1}, u_{j+1}
    float gstage = 0.f;
    if (stager) {
        if (which == 0) {
            ring[0][0][widx] = q[(size_t)1 * D + sidx];
            ring[1][0][widx] = q[(size_t)2 * D + sidx];
            gstage = q[(size_t)3 * D + sidx];
        } else {
            ring[0][1][widx] = U[(size_t)1 * D + sidx];
            ring[1][1][widx] = U[(size_t)2 * D + sidx];
            gstage = U[(size_t)3 * D + sidx];
        }
    }
    // k_0 chunk into registers
    {
        const v4f* kg = (const v4f*)(k + cg * 16);
        const v4f Ka = kg[0], Kb = kg[1], Kc = kg[2], Kd = kg[3];
        k0_ = LO2(Ka); k1_ = HI2(Ka); k2_ = LO2(Kb); k3_ = HI2(Kb);
        k4_ = LO2(Kc); k5_ = HI2(Kc); k6_ = LO2(Kd); k7_ = HI2(Kd);
    }
    float vcur = v[r], vnext = v[(size_t)D + r], vn2 = v[(size_t)2 * D + r];

    // dec_0 is always mode 2 (first step: J_0 = v_0 k_0^T); read at body 0 (phase 0)
    float dwf = 0.f, dwi = 1.f;
    int dmode = 2;
    if (tid == 0) { decLDS[0][0] = 0.f; decLDS[0][1] = 1.f; decLDS[0][2] = 2.f; decLDS[0][3] = 0.f; }

    double SJ = 0.0, AJJ = 0.0, trSvv = 0.0;  // live on wave 0 only
    if (w == 0) {
        const double sl0 = (double)sl_arr[0];
        const double kq0 = (double)kqq_arr[0];
        const double vv0 = (double)vv_arr[0];
        trSvv = vv0;
        SJ  = sl0;
        AJJ = vv0 * kq0;
        if (lane == 0) {
            out[0] = (float)((0.5 * trSvv - SJ + 0.5 * AJJ) * invl_arr[0]);
            out[SEQ] = 1.f;
        }
    }
    __syncthreads();

#define STEP_BODY(I, P, PN, PW)                                               \
{                                                                             \
    float c_sl = 0.f, c_kq = 0.f, c_vv = 0.f, c_kqa = 0.f, c_vva = 0.f,       \
          c_vvp = 0.f, c_kua = 0.f;                                           \
    double c_inv = 0.0;                                                       \
    if (w == 0) {                                                             \
        c_sl  = sl_arr[(I) + 1];  c_kq  = kqq_arr[(I) + 1];                   \
        c_vv  = vv_arr[(I) + 1];  c_kqa = kq_adj[(I) + 1];                    \
        c_vva = vv_adj[(I) + 1];  c_vvp = vv_arr[(I)];                        \
        c_kua = kU_adj[(I) + 1];  c_inv = invl_arr[(I) + 1];                  \
    }                                                                         \
    const v4f Qa = ((const v4f*)&ring[P][0][c0s])[0];                         \
    const v4f Qb = ((const v4f*)&ring[P][0][c0s])[1];                         \
    const v4f Qc = ((const v4f*)&ring[P][0][c0s])[2];                         \
    const v4f Qd = ((const v4f*)&ring[P][0][c0s])[3];                         \
    const v4f Ua = ((const v4f*)&ring[P][1][c0s])[0];                         \
    const v4f Ub = ((const v4f*)&ring[P][1][c0s])[1];                         \
    const v4f Uc = ((const v4f*)&ring[P][1][c0s])[2];                         \
    const v4f Ud = ((const v4f*)&ring[P][1][c0s])[3];                         \
    v2f aq0 = {0.f, 0.f}, aq1 = aq0, aq2 = aq0, aq3 = aq0;                    \
    aq0 = __builtin_elementwise_fma(j0, LO2(Qa), aq0);                        \
    aq1 = __builtin_elementwise_fma(j1, HI2(Qa), aq1);                        \
    aq2 = __builtin_elementwise_fma(j2, LO2(Qb), aq2);                        \
    aq3 = __builtin_elementwise_fma(j3, HI2(Qb), aq3);                        \
    aq0 = __builtin_elementwise_fma(j4, LO2(Qc), aq0);                        \
    aq1 = __builtin_elementwise_fma(j5, HI2(Qc), aq1);                        \
    aq2 = __builtin_elementwise_fma(j6, LO2(Qd), aq2);                        \
    aq3 = __builtin_elementwise_fma(j7, HI2(Qd), aq3);                        \
    const v2f sq_ = (aq0 + aq1) + (aq2 + aq3);                                \
    float Yq = sq_.x + sq_.y;                                                 \
    v2f au0 = {0.f, 0.f}, au1 = au0, au2 = au0, au3 = au0;                    \
    au0 = __builtin_elementwise_fma(j0, LO2(Ua), au0);                        \
    au1 = __builtin_elementwise_fma(j1, HI2(Ua), au1);                        \
    au2 = __builtin_elementwise_fma(j2, LO2(Ub), au2);                        \
    au3 = __builtin_elementwise_fma(j3, HI2(Ub), au3);                        \
    au0 = __builtin_elementwise_fma(j4, LO2(Uc), au0);                        \
    au1 = __builtin_elementwise_fma(j5, HI2(Uc), au1);                        \
    au2 = __builtin_elementwise_fma(j6, LO2(Ud), au2);                        \
    au3 = __builtin_elementwise_fma(j7, HI2(Ud), au3);                        \
    const v2f su_ = (au0 + au1) + (au2 + au3);                                \
    float Yw = su_.x + su_.y;                                                 \
    COMBINE8(Yq);                                                             \
    COMBINE8(Yw);                                                             \
    float z1 = vnext * Yq;                                                    \
    float z2 = Yq * Yq;                                                       \
    float z3 = vcur  * Yq;                                                    \
    float z4 = vnext * Yw;                                                    \
    TAIL3(z1);                                                                \
    TAIL3(z2);                                                                \
    TAIL3(z3);                                                                \
    TAIL3(z4);                                                                \
    if (lane == 63) *(float4*)&wred[P][w][0] = make_float4(z1, z2, z3, z4);   \
    __syncthreads();                                                          \
    /* post-barrier global loads: k_{I+1} chunk, staging, v — all covered */  \
    /* by ~1 full iteration before the next barrier's drain */                \
    const v4f* kgp = (const v4f*)(k + (size_t)((I) + 1) * D + cg * 16);       \
    const v4f Kna = kgp[0], Knb = kgp[1], Knc = kgp[2], Knd = kgp[3];         \
    if (stager) {                                                             \
        ring[PW][which][widx] = gstage;                                       \
        const int tq_ = ((I) + 4 < SEQ) ? (I) + 4 : SEQ - 1;                  \
        gstage = (which == 0) ? q[(size_t)tq_ * D + sidx]                     \
                              : U[(size_t)tq_ * D + sidx];                    \
    }                                                                         \
    const int tv_ = ((I) + 3 < SEQ) ? (I) + 3 : SEQ - 1;                      \
    const float vnew_ = v[(size_t)tv_ * D + r];                               \
    if (w == 0) {                                                             \
        float4 ww = *(const float4*)&wred[P][lane & 15][0];                   \
        const float odwf = dwf, odwi = dwi;                                   \
        const int   odmode = dmode;                                           \
        UPDATE_J(odmode, odwf, odwi)                                          \
        REDUCE16(ww.x);                                                       \
        REDUCE16(ww.y);                                                       \
        REDUCE16(ww.z);                                                       \
        REDUCE16(ww.w);                                                       \
        double a_, b_;                                                        \
        if (odmode == 2)      { a_ = 0.0; b_ = 1.0; }                         \
        else if (odmode == 1) { a_ = (double)odwf; b_ = (double)odwi; }       \
        else                  { a_ = 1.0; b_ = 0.0; }                         \
        const double kqa = (double)c_kqa, vva = (double)c_vva;                \
        const double vvp = (double)c_vvp, kua = (double)c_kua;                \
        const double r1 = (double)ww.x * 0.125, r2 = (double)ww.y * 0.125;    \
        const double r3 = (double)ww.z * 0.125, r4 = (double)ww.w * 0.125;    \
        const double Jqv  = a_ * r1 + b_ * (kqa * vva);                       \
        const double Jq2  = a_ * a_ * r2 + 2.0 * a_ * b_ * kqa * r3          \
                          + b_ * b_ * kqa * kqa * vvp;                        \
        const double AJl_ = a_ * r4 + b_ * kua * vva;                         \
        trSvv += (double)c_vv;                                                \
        SJ    += Jqv;                                                         \
        AJJ   += Jq2;                                                         \
        const double s_l  = (double)c_sl;                                     \
        const double A_ll = (double)c_vv * (double)c_kq;                      \
        const double AJJ_s  = (AJJ == 0.0)  ? 1.0 : AJJ;                      \
        const double A_ll_s = (A_ll == 0.0) ? 1.0 : A_ll;                     \
        const double denom   = AJJ * A_ll - AJl_ * AJl_;                      \
        const double denom_s = (denom == 0.0) ? 1.0 : denom;                  \
        const double rden = 1.0 / denom_s;                                    \
        const double wf = (A_ll * SJ - AJl_ * s_l) * rden;                    \
        const double wi = (AJJ * s_l - AJl_ * SJ) * rden;                     \
        double wf_c, wi_c;                                                    \
        if (wi <= 0.0)      { wf_c = SJ / AJJ_s;  wi_c = 0.0; }               \
        else if (wf <= 0.0) { wf_c = 0.0;         wi_c = s_l / A_ll_s; }      \
        else                { wf_c = wf;          wi_c = wi; }                \
        const bool do_update = (s_l * AJJ_s - AJl_ * SJ) > 0.0;               \
        int mode;                                                             \
        if (do_update) {                                                      \
            mode = 1;                                                         \
            const double nSJ = wf_c * SJ + wi_c * s_l;                        \
            AJJ = wf_c * wf_c * AJJ + 2.0 * wf_c * wi_c * AJl_                \
                + wi_c * wi_c * A_ll;                                         \
            SJ = nSJ;                                                         \
        } else {                                                              \
            mode = 0;                                                         \
        }                                                                     \
        dwf = (float)wf_c; dwi = (float)wi_c; dmode = mode;                   \
        if (lane == 0) {                                                      \
            out[(I) + 1] = (float)((0.5 * trSvv - SJ + 0.5 * AJJ) * c_inv);   \
            out[SEQ + (I) + 1] = mode ? 1.f : 0.f;                            \
            *(float4*)&decLDS[PN][0] = make_float4(dwf, dwi, (float)mode, 0.f);\
        }                                                                     \
    } else {                                                                  \
        const float4 df = *(const float4*)&decLDS[P][0];                      \
        dwf = df.x; dwi = df.y; dmode = (int)df.z;                            \
        UPDATE_J(dmode, dwf, dwi)                                             \
    }                                                                         \
    /* shift k pipeline (update above used the OLD k_i) */                    \
    k0_ = LO2(Kna); k1_ = HI2(Kna); k2_ = LO2(Knb); k3_ = HI2(Knb);           \
    k4_ = LO2(Knc); k5_ = HI2(Knc); k6_ = LO2(Knd); k7_ = HI2(Knd);           \
    vcur = vnext; vnext = vn2; vn2 = vnew_;                                   \
}

    // bodies I = 0..SEQ-2 (2047 of them): 682 x3-unrolled + 1 tail (2046%3==0)
    for (int i = 0; i + 2 < SEQ - 1; i += 3) {
        STEP_BODY(i,     0, 1, 2)
        STEP_BODY(i + 1, 1, 2, 0)
        STEP_BODY(i + 2, 2, 0, 1)
    }
    STEP_BODY(SEQ - 2, 0, 1, 2)
#undef STEP_BODY

    // ---- epilogue: apply final update (dec_{SEQ-1}; k_{SEQ-1} in registers) ----
    __syncthreads();  // make wave0's decLDS[1] write visible
    {
        const float4 df = *(const float4*)&decLDS[1][0];
        const float fwf = df.x, fwi = df.y;
        const int   fmode = (int)df.z;
        UPDATE_J(fmode, fwf, fwi)
        float* jbase = out + 2 * SEQ + (size_t)r * D + cg * 16;
        *(v4f*)(jbase + 0)  = __builtin_shufflevector(j0, j1, 0, 1, 2, 3);
        *(v4f*)(jbase + 4)  = __builtin_shufflevector(j2, j3, 0, 1, 2, 3);
        *(v4f*)(jbase + 8)  = __builtin_shufflevector(j4, j5, 0, 1, 2, 3);
        *(v4f*)(jbase + 12) = __builtin_shufflevector(j6, j7, 0, 1, 2, 3);
    }
}

extern "C" void kernel_launch(void* const* d_in, const int* in_sizes, int n_in,
                              void* d_out, int out_size, void* d_ws, size_t ws_size,
                              hipStream_t stream) {
    (void)in_sizes; (void)n_in; (void)out_size; (void)ws_size;
    const float* q = (const float*)d_in[0];
    const float* k = (const float*)d_in[1];
    const float* v = (const float*)d_in[2];
    float* out = (float*)d_out;

    float* U      = (float*)d_ws;            // SEQ*D floats (1 MB)
    float* sl     = U + (size_t)SEQ * D;     // SEQ
    float* kqq    = sl + SEQ;                // SEQ
    float* vv     = kqq + SEQ;               // SEQ
    float* kq_adj = vv + SEQ;                // SEQ
    float* vv_adj = kq_adj + SEQ;            // SEQ
    float* kU_adj = vv_adj + SEQ;            // SEQ
    double* invl  = (double*)(kU_adj + SEQ); // SEQ doubles (8B-aligned)

    precompute_kernel<<<SEQ, 256, 0, stream>>>(q, k, v, U, sl, kqq, vv,
                                               kq_adj, vv_adj, kU_adj, invl);
    scan_kernel<<<1, 1024, 0, stream>>>(q, k, v, U, sl, kqq, vv,
                                        kq_adj, vv_adj, kU_adj, invl, out);
}